// Round 15
// baseline (584.908 us; speedup 1.0000x reference)
//
#include <hip/hip_runtime.h>

// Luenberger state estimator: T=2048 sequential steps, B=1024 independent
// elements. 1 wave/element (1024 blocks x 64 threads), lane h = hidden unit h
// of BOTH MLPs. R15 = R13 (proven 577us) + packed error only:
//  - ep = pk_fma(cy, m1, ya)  (2 scalar subs -> 1 packed fma; inputs are a
//    waitcnt-tracked load value and an inline-asm VOP3P output -- safe class)
//  - tanh tail stays R13's tanh_pair: exp2/rcp results are consumed by
//    COMPILER-generated fmaf. R14 post-mortem: feeding TRANS-op results
//    (v_exp/v_rcp) straight into inline-asm pk_fma skips the hazard nops
//    (same mechanism as R10's raw-DPP failure) -> NaN. HW rule: never feed
//    TRANS or DPP results directly into inline asm.
// Everything else byte-identical to R13 (splat-x dots, op_sel c-block,
// swap32+swap16 folds with validated probe, kof-permuted output weights,
// builtin-DPP prefix, ping-pong prefetch, R11 fallback path).

#define T_STEPS 2048
#define B_SZ    1024
#define NX      8
#define HID     64

typedef float v2f __attribute__((ext_vector_type(2)));

// d = a*b + c
__device__ __forceinline__ v2f pk_fma(v2f a, v2f b, v2f c) {
  v2f d;
  asm("v_pk_fma_f32 %0, %1, %2, %3" : "=v"(d) : "v"(a), "v"(b), "v"(c));
  return d;
}
// d = splat_lo(a)*b + c   (PROVEN R6)
__device__ __forceinline__ v2f pk_fma_s0lo(v2f a, v2f b, v2f c) {
  v2f d;
  asm("v_pk_fma_f32 %0, %1, %2, %3 op_sel:[0,0,0] op_sel_hi:[0,1,1]"
      : "=v"(d) : "v"(a), "v"(b), "v"(c));
  return d;
}
// d = splat_hi(a)*b + c   (PROVEN R6)
__device__ __forceinline__ v2f pk_fma_s0hi(v2f a, v2f b, v2f c) {
  v2f d;
  asm("v_pk_fma_f32 %0, %1, %2, %3 op_sel:[1,0,0] op_sel_hi:[1,1,1]"
      : "=v"(d) : "v"(a), "v"(b), "v"(c));
  return d;
}
// acc += a*splat_lo(b)    (PROVEN R6)
__device__ __forceinline__ void pk_fma_acc_s1lo(v2f& acc, v2f a, v2f b) {
  asm("v_pk_fma_f32 %0, %1, %2, %0 op_sel:[0,0,0] op_sel_hi:[1,0,1]"
      : "+v"(acc) : "v"(a), "v"(b));
}
// acc += a*splat_hi(b)    (PROVEN R6)
__device__ __forceinline__ void pk_fma_acc_s1hi(v2f& acc, v2f a, v2f b) {
  asm("v_pk_fma_f32 %0, %1, %2, %0 op_sel:[0,1,0] op_sel_hi:[1,1,1]"
      : "+v"(acc) : "v"(a), "v"(b));
}

// tanh pair: inputs pre-scaled by 2*log2(e); returns {tanh(a), tanh(b)}
// TRANS results consumed by compiler-generated ops ONLY (hazard-safe).
__device__ __forceinline__ v2f tanh_pair(float pa, float pb) {
  v2f r;
  r[0] = __builtin_amdgcn_rcpf(__builtin_amdgcn_exp2f(pa) + 1.0f);
  r[1] = __builtin_amdgcn_rcpf(__builtin_amdgcn_exp2f(pb) + 1.0f);
  v2f h;
  h[0] = fmaf(-2.0f, r[0], 1.0f);
  h[1] = fmaf(-2.0f, r[1], 1.0f);
  return h;
}

template <int CTRL, int RMASK>
__device__ __forceinline__ float dpp_add(float acc) {
  int moved = __builtin_amdgcn_update_dpp(0, __float_as_int(acc), CTRL, RMASK, 0xf, true);
  return acc + __int_as_float(moved);
}

// 4-stage row prefix (builtin DPP): lanes {15,31,47,63} end with their row sum
__device__ __forceinline__ float prefix16(float c) {
  c = dpp_add<0x111, 0xf>(c);  // row_shr:1
  c = dpp_add<0x112, 0xf>(c);  // row_shr:2
  c = dpp_add<0x114, 0xf>(c);  // row_shr:4
  c = dpp_add<0x118, 0xf>(c);  // row_shr:8
  return c;
}
// 5-stage: lane 31 = sum(0..31), lane 63 = sum(32..63)  (PROVEN R3/R6/R11)
__device__ __forceinline__ float half_reduce(float c) {
  c = prefix16(c);
  c = dpp_add<0x142, 0xa>(c);  // row_bcast:15 into rows 1,3
  return c;
}

__device__ __forceinline__ void swap32(float& a, float& b) {
  asm("v_permlane32_swap_b32 %0, %1" : "+v"(a), "+v"(b));
}
__device__ __forceinline__ void swap16(float& a, float& b) {
  asm("v_permlane16_swap_b32 %0, %1" : "+v"(a), "+v"(b));
}

__device__ __forceinline__ float rlf(float v, int lane) {
  return __int_as_float(__builtin_amdgcn_readlane(__float_as_int(v), lane));
}

__global__ __launch_bounds__(64, 1) void luen_kernel(
    const float* __restrict__ u, const float* __restrict__ y,
    const float* __restrict__ Wf1, const float* __restrict__ bf1,
    const float* __restrict__ Wf2, const float* __restrict__ bf2,
    const float* __restrict__ Wg, const float* __restrict__ bg,
    const float* __restrict__ Wk1, const float* __restrict__ bk1,
    const float* __restrict__ Wk2, const float* __restrict__ bk2,
    float* __restrict__ out) {
  const int eb = blockIdx.x;
  const int h  = threadIdx.x;

  const float TS = 2.885390081777927f;  // 2*log2(e)
  const float INV64 = 1.0f / 64.0f;

  // VGPR-resident constant pair for packed error
  const v2f m1 = v2f{-1.0f, -1.0f};

  // ---- permlane32_swap direction probe (non-uniform; PROVEN R3/R6) ----
  float probe = (h < 32) ? 0.0f : 1.0f;
  float zf = 0.0f;
  swap32(probe, zf);
  const bool dir1 = __builtin_amdgcn_readlane(__float_as_int(probe), 32) != 0;
  const int laneA = dir1 ? 63 : 31;  // sum of c[j]   (fallback path)
  const int laneB = dir1 ? 31 : 63;  // sum of c[j+4] (fallback path)

  // ---- swap16 mapping probe, per-half power-of-2 markers (PROVEN R12) ----
  int kof[8];
  bool fastok;
  {
    float dP[4];
#pragma unroll
    for (int j = 0; j < 4; ++j) {
      const float hiM = dir1 ? (float)(1 << j) : (float)(1 << (j + 4));
      const float loM = dir1 ? (float)(1 << (j + 4)) : (float)(1 << j);
      dP[j] = (h < 32) ? loM : hiM;
    }
    swap16(dP[0], dP[1]); float ffP = dP[0] + dP[1];
    swap16(dP[2], dP[3]); float ggP = dP[2] + dP[3];
    ffP = prefix16(ffP);
    ggP = prefix16(ggP);
    float sv[8];
    sv[0] = rlf(ffP, 15); sv[1] = rlf(ffP, 31);
    sv[2] = rlf(ffP, 47); sv[3] = rlf(ffP, 63);
    sv[4] = rlf(ggP, 15); sv[5] = rlf(ggP, 31);
    sv[6] = rlf(ggP, 47); sv[7] = rlf(ggP, 63);
    int jm[8];
    fastok = true;
    int seen = 0;
#pragma unroll
    for (int s = 0; s < 8; ++s) {
      const float r = sv[s] * 0.03125f;      // /32; each slot must be 32*2^j
      const int iv = (int)r;
      const bool ok = ((float)iv == r) && iv > 0 && iv <= 128 &&
                      ((iv & (iv - 1)) == 0);
      const int j = ok ? __builtin_ctz(iv) : 0;
      jm[s] = j;
      seen |= ok ? (1 << j) : 0;
      fastok = fastok && ok;
    }
    fastok = fastok && (seen == 0xFF);       // bijective
#pragma unroll
    for (int j = 0; j < 8; ++j) {
      if (fastok) {
        int v = 0;
#pragma unroll
        for (int s = 0; s < 8; ++s) v += (jm[s] == j) ? s : 0;
        kof[j] = v;                          // kof = jm^{-1}
      } else {
        kof[j] = j;                          // identity for fallback path
      }
    }
  }

  // ---- input-side weights: fused f/k prenet pairs + yhat row pairs ----
  v2f wfk[8];
#pragma unroll
  for (int k = 0; k < 8; ++k)
    wfk[k] = v2f{TS * Wf1[k * HID + h], TS * Wk1[k * HID + h]};
  const float uf8 = TS * Wf1[8 * HID + h];
  const float uf9 = TS * Wf1[9 * HID + h];
  const v2f hb = v2f{TS * bf1[h], TS * bk1[h]};
  v2f wgp[8];
#pragma unroll
  for (int k = 0; k < 8; ++k) wgp[k] = v2f{Wg[2 * k], Wg[2 * k + 1]};
  const v2f bgp = v2f{bg[0], bg[1]};

  // ---- output side: permuted by kof (identity when fallback) ----
  v2f wf2p[4], bf2sp[4], wk2e[4], wk2o[4], bk2se[4], bk2so[4];
  {
    const float* wf2row = Wf2 + h * NX;
    const float* wk2row = Wk2 + h * (NX * 2);
#pragma unroll
    for (int p = 0; p < 4; ++p) {
      const int kl = kof[2 * p], kh = kof[2 * p + 1];
      wf2p[p]  = v2f{wf2row[kl], wf2row[kh]};
      bf2sp[p] = v2f{INV64 * bf2[kl], INV64 * bf2[kh]};
      wk2e[p]  = v2f{wk2row[2 * kl], wk2row[2 * kh]};
      wk2o[p]  = v2f{wk2row[2 * kl + 1], wk2row[2 * kh + 1]};
      bk2se[p] = v2f{INV64 * bk2[2 * kl], INV64 * bk2[2 * kh]};
      bk2so[p] = v2f{INV64 * bk2[2 * kl + 1], INV64 * bk2[2 * kh + 1]};
    }
  }

  const v2f* __restrict__ pu = reinterpret_cast<const v2f*>(u) + eb;
  const v2f* __restrict__ py = reinterpret_cast<const v2f*>(y) + eb;
  const int STR = B_SZ;

  v2f x2[4];
#pragma unroll
  for (int p = 0; p < 4; ++p) x2[p] = v2f{0.0f, 0.0f};

  v2f Au[4], Ay[4], Bu[4], By[4];

#define LOADG(SET_u, SET_y)                          \
  {                                                  \
    SET_u[0] = pu[0 * STR]; SET_u[1] = pu[1 * STR];  \
    SET_u[2] = pu[2 * STR]; SET_u[3] = pu[3 * STR];  \
    SET_y[0] = py[0 * STR]; SET_y[1] = py[1 * STR];  \
    SET_y[2] = py[2 * STR]; SET_y[3] = py[3 * STR];  \
    pu += 4 * STR; py += 4 * STR;                    \
  }

#define STEP(CU_, CY_)                                                        \
  {                                                                           \
    const v2f cu = (CU_);                                                     \
    const v2f cy = (CY_);                                                     \
    /* packed yhat: ya = sum_k splat(x[k]) * {Wg[k][0],Wg[k][1]} */           \
    v2f ya = pk_fma_s0lo(x2[0], wgp[0], bgp);                                 \
    pk_fma_acc_s1hi(ya, wgp[1], x2[0]);                                       \
    pk_fma_acc_s1lo(ya, wgp[2], x2[1]);                                       \
    pk_fma_acc_s1hi(ya, wgp[3], x2[1]);                                       \
    pk_fma_acc_s1lo(ya, wgp[4], x2[2]);                                       \
    pk_fma_acc_s1hi(ya, wgp[5], x2[2]);                                       \
    pk_fma_acc_s1lo(ya, wgp[6], x2[3]);                                       \
    pk_fma_acc_s1hi(ya, wgp[7], x2[3]);                                       \
    const v2f ep = pk_fma(cy, m1, ya);   /* ep = ya - cy, packed (R15) */     \
    /* fused prenet: pre = sum_k splat(x[k]) * {f_k, k_k} (+u into f half) */ \
    v2f pre = pk_fma_s0lo(x2[0], wfk[0], hb);                                 \
    pk_fma_acc_s1hi(pre, wfk[1], x2[0]);                                      \
    pk_fma_acc_s1lo(pre, wfk[2], x2[1]);                                      \
    pk_fma_acc_s1hi(pre, wfk[3], x2[1]);                                      \
    pk_fma_acc_s1lo(pre, wfk[4], x2[2]);                                      \
    pk_fma_acc_s1hi(pre, wfk[5], x2[2]);                                      \
    pk_fma_acc_s1lo(pre, wfk[6], x2[3]);                                      \
    pk_fma_acc_s1hi(pre, wfk[7], x2[3]);                                      \
    pre[0] = fmaf(cu[0], uf8, pre[0]);                                        \
    pre[0] = fmaf(cu[1], uf9, pre[0]);                                        \
    const v2f hp = tanh_pair(pre[0], pre[1]);                                 \
    /* per-lane contributions: op_sel splats (PROVEN R6) */                   \
    float c0, c1, c2, c3, c4, c5, c6, c7;                                     \
    {                                                                         \
      v2f t0 = pk_fma_s0hi(hp, wk2e[0], bk2se[0]);                            \
      v2f t1 = pk_fma_s0hi(hp, wk2o[0], bk2so[0]);                            \
      v2f cp = pk_fma_s0lo(hp, wf2p[0], bf2sp[0]);                            \
      pk_fma_acc_s1lo(cp, t0, ep);                                            \
      pk_fma_acc_s1hi(cp, t1, ep);                                            \
      c0 = cp[0]; c1 = cp[1];                                                 \
    }                                                                         \
    {                                                                         \
      v2f t0 = pk_fma_s0hi(hp, wk2e[1], bk2se[1]);                            \
      v2f t1 = pk_fma_s0hi(hp, wk2o[1], bk2so[1]);                            \
      v2f cp = pk_fma_s0lo(hp, wf2p[1], bf2sp[1]);                            \
      pk_fma_acc_s1lo(cp, t0, ep);                                            \
      pk_fma_acc_s1hi(cp, t1, ep);                                            \
      c2 = cp[0]; c3 = cp[1];                                                 \
    }                                                                         \
    {                                                                         \
      v2f t0 = pk_fma_s0hi(hp, wk2e[2], bk2se[2]);                            \
      v2f t1 = pk_fma_s0hi(hp, wk2o[2], bk2so[2]);                            \
      v2f cp = pk_fma_s0lo(hp, wf2p[2], bf2sp[2]);                            \
      pk_fma_acc_s1lo(cp, t0, ep);                                            \
      pk_fma_acc_s1hi(cp, t1, ep);                                            \
      c4 = cp[0]; c5 = cp[1];                                                 \
    }                                                                         \
    {                                                                         \
      v2f t0 = pk_fma_s0hi(hp, wk2e[3], bk2se[3]);                            \
      v2f t1 = pk_fma_s0hi(hp, wk2o[3], bk2so[3]);                            \
      v2f cp = pk_fma_s0lo(hp, wf2p[3], bf2sp[3]);                            \
      pk_fma_acc_s1lo(cp, t0, ep);                                            \
      pk_fma_acc_s1hi(cp, t1, ep);                                            \
      c6 = cp[0]; c7 = cp[1];                                                 \
    }                                                                         \
    /* PROVEN swap32 fold */                                                  \
    swap32(c0, c4); float d0 = c0 + c4;                                       \
    swap32(c1, c5); float d1 = c1 + c5;                                       \
    swap32(c2, c6); float d2 = c2 + c6;                                       \
    swap32(c3, c7); float d3 = c3 + c7;                                       \
    if (fastok) {                                                             \
      /* PROVEN R12 two-level: swap16 fold + 4-stage builtin-DPP prefix */    \
      swap16(d0, d1); float ff = d0 + d1;                                     \
      swap16(d2, d3); float gg = d2 + d3;                                     \
      ff = prefix16(ff);                                                      \
      gg = prefix16(gg);                                                      \
      x2[0][0] += rlf(ff, 15); x2[0][1] += rlf(ff, 31);                       \
      x2[1][0] += rlf(ff, 47); x2[1][1] += rlf(ff, 63);                       \
      x2[2][0] += rlf(gg, 15); x2[2][1] += rlf(gg, 31);                       \
      x2[3][0] += rlf(gg, 47); x2[3][1] += rlf(gg, 63);                       \
    } else {                                                                  \
      /* exact R11 path (kof == identity) */                                  \
      d0 = half_reduce(d0); d1 = half_reduce(d1);                             \
      d2 = half_reduce(d2); d3 = half_reduce(d3);                             \
      x2[0][0] += rlf(d0, laneA); x2[0][1] += rlf(d1, laneA);                 \
      x2[1][0] += rlf(d2, laneA); x2[1][1] += rlf(d3, laneA);                 \
      x2[2][0] += rlf(d0, laneB); x2[2][1] += rlf(d1, laneB);                 \
      x2[3][0] += rlf(d2, laneB); x2[3][1] += rlf(d3, laneB);                 \
    }                                                                         \
  }

  LOADG(Au, Ay);
  LOADG(Bu, By);

  for (int it = 0; it < 255; ++it) {
    STEP(Au[0], Ay[0]); STEP(Au[1], Ay[1]); STEP(Au[2], Ay[2]); STEP(Au[3], Ay[3]);
    LOADG(Au, Ay);
    STEP(Bu[0], By[0]); STEP(Bu[1], By[1]); STEP(Bu[2], By[2]); STEP(Bu[3], By[3]);
    LOADG(Bu, By);
  }
  STEP(Au[0], Ay[0]); STEP(Au[1], Ay[1]); STEP(Au[2], Ay[2]); STEP(Au[3], Ay[3]);
  STEP(Bu[0], By[0]); STEP(Bu[1], By[1]); STEP(Bu[2], By[2]); STEP(Bu[3], By[3]);
#undef STEP
#undef LOADG

  if (h == 0) {
#pragma unroll
    for (int p = 0; p < 4; ++p) {
      out[eb * NX + 2 * p]     = x2[p][0];
      out[eb * NX + 2 * p + 1] = x2[p][1];
    }
  }
}

extern "C" void kernel_launch(void* const* d_in, const int* in_sizes, int n_in,
                              void* d_out, int out_size, void* d_ws, size_t ws_size,
                              hipStream_t stream) {
  const float* u   = (const float*)d_in[0];
  const float* y   = (const float*)d_in[1];
  const float* Wf1 = (const float*)d_in[2];
  const float* bf1 = (const float*)d_in[3];
  const float* Wf2 = (const float*)d_in[4];
  const float* bf2 = (const float*)d_in[5];
  const float* Wg  = (const float*)d_in[6];
  const float* bg  = (const float*)d_in[7];
  const float* Wk1 = (const float*)d_in[8];
  const float* bk1 = (const float*)d_in[9];
  const float* Wk2 = (const float*)d_in[10];
  const float* bk2 = (const float*)d_in[11];

  luen_kernel<<<dim3(B_SZ), dim3(HID), 0, stream>>>(
      u, y, Wf1, bf1, Wf2, bf2, Wg, bg, Wk1, bk1, Wk2, bk2, (float*)d_out);
}